// Round 4
// baseline (696.540 us; speedup 1.0000x reference)
//
#include <hip/hip_runtime.h>
#include <hip/hip_bf16.h>
#include <stdint.h>

// Problem constants (fixed by setup_inputs)
#define BATCH    8
#define NTOKB    4096                 // tokens per batch
#define NTOK     (BATCH * NTOKB)     // 32768
#define DIN      512
#define DD       512                 // TOKEN_DIM * NUM_HEADS
#define TD       256                 // TOKEN_DIM
#define SCALE    0.0625f             // 256^-0.5

typedef unsigned short ushortT;

__device__ __forceinline__ float bf_lo(uint32_t u) { return __uint_as_float(u << 16); }
__device__ __forceinline__ float bf_hi(uint32_t u) { return __uint_as_float(u & 0xffff0000u); }
__device__ __forceinline__ float bf2f(ushortT u) { return __uint_as_float(((uint32_t)u) << 16); }
// round-to-nearest-even f32 -> bf16
__device__ __forceinline__ ushortT f2bf(float f) {
    uint32_t u = __float_as_uint(f);
    return (ushortT)((u + 0x7fffu + ((u >> 16) & 1u)) >> 16);
}

// ---------------------------------------------------------------------------
// K1: per 16-token tile: q = l2norm(x@Wq+bq), k = l2norm(x@Wk+bk), stored bf16.
// Also alpha_raw[tok] = SCALE * dot(q_norm, w_alpha).
// 256 threads: tid<128 -> q (4 cols each), tid>=128 -> k.
// ---------------------------------------------------------------------------
__global__ __launch_bounds__(256) void qk_kernel(
    const float* __restrict__ x, const float* __restrict__ Wq, const float* __restrict__ bq,
    const float* __restrict__ Wk, const float* __restrict__ bk,
    const float* __restrict__ w_alpha,
    ushortT* __restrict__ qn, ushortT* __restrict__ kn, float* __restrict__ alpha_raw)
{
    __shared__ float xs[16 * 512];     // x tile fp32 (32 KB)
    __shared__ float ps[256 * 16];     // per-thread partials (ssq, then alpha)
    __shared__ float invq[16], invk[16];

    const int tid = threadIdx.x;
    const size_t tok0 = (size_t)blockIdx.x * 16;

    // ---- load x tile (16 tokens x 512 fp32) -> LDS
    {
        const float4* src = reinterpret_cast<const float4*>(x + tok0 * DIN);
        #pragma unroll
        for (int it = 0; it < 8; ++it) {
            int idx = it * 1024 + tid * 4;
            *reinterpret_cast<float4*>(&xs[idx]) = src[idx >> 2];
        }
    }

    const bool is_q = (tid < 128);
    const int j0 = (tid & 127) * 4;
    const float* W    = is_q ? Wq : Wk;
    const float* bias = is_q ? bq : bk;

    float acc[16][4];
    {
        float b0 = bias[j0], b1 = bias[j0 + 1], b2 = bias[j0 + 2], b3 = bias[j0 + 3];
        #pragma unroll
        for (int t = 0; t < 16; ++t) { acc[t][0] = b0; acc[t][1] = b1; acc[t][2] = b2; acc[t][3] = b3; }
    }
    __syncthreads();

    // ---- main GEMM loop: 512 k-steps, unrolled by 2
    for (int i = 0; i < 512; i += 2) {
        float4 w0 = *reinterpret_cast<const float4*>(W + (size_t)i * DD + j0);
        float4 w1 = *reinterpret_cast<const float4*>(W + (size_t)(i + 1) * DD + j0);
        #pragma unroll
        for (int t = 0; t < 16; ++t) {
            float2 xv = *reinterpret_cast<const float2*>(&xs[t * 512 + i]);  // wave-broadcast
            acc[t][0] = fmaf(xv.y, w1.x, fmaf(xv.x, w0.x, acc[t][0]));
            acc[t][1] = fmaf(xv.y, w1.y, fmaf(xv.x, w0.y, acc[t][1]));
            acc[t][2] = fmaf(xv.y, w1.z, fmaf(xv.x, w0.z, acc[t][2]));
            acc[t][3] = fmaf(xv.y, w1.w, fmaf(xv.x, w0.w, acc[t][3]));
        }
    }

    // ---- per-token sum of squares -> inverse norms
    #pragma unroll
    for (int t = 0; t < 16; ++t) {
        ps[tid * 16 + t] = acc[t][0] * acc[t][0] + acc[t][1] * acc[t][1]
                         + acc[t][2] * acc[t][2] + acc[t][3] * acc[t][3];
    }
    __syncthreads();
    if (tid < 32) {
        int t = tid & 15;
        int base = (tid < 16) ? 0 : 128;
        float s = 0.f;
        for (int th = 0; th < 128; ++th) s += ps[(base + th) * 16 + t];
        float inv = 1.0f / fmaxf(sqrtf(s), 1e-12f);
        if (tid < 16) invq[t] = inv; else invk[t] = inv;
    }
    __syncthreads();

    // ---- normalize, store bf16, q-half computes alpha partials
    float wa0 = 0.f, wa1 = 0.f, wa2 = 0.f, wa3 = 0.f;
    if (is_q) {
        wa0 = w_alpha[j0];     wa1 = w_alpha[j0 + 1];
        wa2 = w_alpha[j0 + 2]; wa3 = w_alpha[j0 + 3];
    }
    ushortT* dst = is_q ? qn : kn;
    #pragma unroll
    for (int t = 0; t < 16; ++t) {
        float inv = is_q ? invq[t] : invk[t];
        float v0 = acc[t][0] * inv, v1 = acc[t][1] * inv;
        float v2 = acc[t][2] * inv, v3 = acc[t][3] * inv;
        ushort4 st;
        st.x = f2bf(v0); st.y = f2bf(v1); st.z = f2bf(v2); st.w = f2bf(v3);
        *reinterpret_cast<ushort4*>(dst + (tok0 + t) * DD + j0) = st;
        if (is_q) ps[tid * 16 + t] = v0 * wa0 + v1 * wa1 + v2 * wa2 + v3 * wa3;
    }
    __syncthreads();
    if (tid < 16) {
        float s = 0.f;
        for (int th = 0; th < 128; ++th) s += ps[th * 16 + tid];
        alpha_raw[tok0 + tid] = SCALE * s;
    }
}

// ---------------------------------------------------------------------------
// K2: per-batch inverse L2 norm of a [4096] vector
// ---------------------------------------------------------------------------
__global__ __launch_bounds__(256) void norm_kernel(const float* __restrict__ in,
                                                   float* __restrict__ inv_out)
{
    int b = blockIdx.x;
    __shared__ float red[256];
    float s = 0.f;
    for (int i = threadIdx.x; i < NTOKB; i += 256) {
        float v = in[b * NTOKB + i];
        s = fmaf(v, v, s);
    }
    red[threadIdx.x] = s;
    __syncthreads();
    for (int off = 128; off > 0; off >>= 1) {
        if (threadIdx.x < off) red[threadIdx.x] += red[threadIdx.x + off];
        __syncthreads();
    }
    if (threadIdx.x == 0) inv_out[b] = 1.0f / fmaxf(sqrtf(red[0]), 1e-12f);
}

// ---------------------------------------------------------------------------
// K3: dst[b,d] += sum_i raw[b,i]*inv[b] * M[b,i,d]   (fp32 atomics; dst pre-zeroed)
// grid = 256 blocks: b(8) x colchunk(2) x iseg(16); M is bf16
// ---------------------------------------------------------------------------
__global__ __launch_bounds__(256) void wsum_kernel(const ushortT* __restrict__ M,
                                                   const float* __restrict__ raw,
                                                   const float* __restrict__ invp,
                                                   float* __restrict__ dst)
{
    int blk = blockIdx.x;
    int b = blk >> 5;
    int r = blk & 31;
    int d0 = (r >> 4) * 256 + threadIdx.x;
    int i0 = (r & 15) * 256;
    const size_t rowbase = (size_t)b * NTOKB + i0;
    float acc = 0.f;
    for (int ii = 0; ii < 256; ++ii) {
        float w = raw[rowbase + ii];
        acc = fmaf(w, bf2f(M[(rowbase + ii) * DD + d0]), acc);
    }
    atomicAdd(&dst[b * DD + d0], acc * invp[b]);
}

// ---------------------------------------------------------------------------
// K4: per-batch softmax over 512; optional elementwise premultiplier and
// optional wb2 = softmax * w_beta output.
// ---------------------------------------------------------------------------
__global__ __launch_bounds__(256) void softmax_kernel(const float* __restrict__ in,
                                                      const float* __restrict__ mul,
                                                      const float* __restrict__ wbeta,
                                                      float* __restrict__ out,
                                                      float* __restrict__ wb2)
{
    int b = blockIdx.x, tid = threadIdx.x;
    __shared__ float red[256];
    float v0 = in[b * DD + tid], v1 = in[b * DD + 256 + tid];
    if (mul) { v0 *= mul[b * DD + tid]; v1 *= mul[b * DD + 256 + tid]; }
    red[tid] = fmaxf(v0, v1);
    __syncthreads();
    for (int off = 128; off > 0; off >>= 1) {
        if (tid < off) red[tid] = fmaxf(red[tid], red[tid + off]);
        __syncthreads();
    }
    float m = red[0];
    __syncthreads();
    float e0 = expf(v0 - m), e1 = expf(v1 - m);
    red[tid] = e0 + e1;
    __syncthreads();
    for (int off = 128; off > 0; off >>= 1) {
        if (tid < off) red[tid] += red[tid + off];
        __syncthreads();
    }
    float rs = 1.0f / red[0];
    float o0 = e0 * rs, o1 = e1 * rs;
    out[b * DD + tid] = o0;
    out[b * DD + 256 + tid] = o1;
    if (wb2) {
        wb2[b * DD + tid]       = o0 * wbeta[tid];
        wb2[b * DD + 256 + tid] = o1 * wbeta[256 + tid];
    }
}

// ---------------------------------------------------------------------------
// K5: beta_raw[tok] = SCALE * dot(kn[tok,:], wb2[b,:])  — one wave per token
// ---------------------------------------------------------------------------
__global__ __launch_bounds__(256) void beta_kernel(const ushortT* __restrict__ kn,
                                                   const float* __restrict__ wb2,
                                                   float* __restrict__ beta_raw)
{
    int wave = threadIdx.x >> 6, lane = threadIdx.x & 63;
    size_t tok = (size_t)blockIdx.x * 4 + wave;
    int b = (int)(tok >> 12);
    uint4 kv = *reinterpret_cast<const uint4*>(kn + tok * DD + lane * 8);
    float4 wv0 = *reinterpret_cast<const float4*>(wb2 + b * DD + lane * 8);
    float4 wv1 = *reinterpret_cast<const float4*>(wb2 + b * DD + lane * 8 + 4);
    float s = bf_lo(kv.x) * wv0.x + bf_hi(kv.x) * wv0.y
            + bf_lo(kv.y) * wv0.z + bf_hi(kv.y) * wv0.w
            + bf_lo(kv.z) * wv1.x + bf_hi(kv.z) * wv1.y
            + bf_lo(kv.w) * wv1.z + bf_hi(kv.w) * wv1.w;
    #pragma unroll
    for (int off = 32; off > 0; off >>= 1) s += __shfl_xor(s, off);
    if (lane == 0) beta_raw[tok] = SCALE * s;
}

// ---------------------------------------------------------------------------
// K8: out = (g_k*kn + qn) @ Wr + br, per 16-token tile. Output fp32.
// NOTE: kn ALIASES d_out (token t = bytes [t*1024, t*1024+1024) in both).
// Safe: each block stages its own 16-token kn range into LDS (+barrier)
// before the epilogue overwrites exactly that byte range; no cross-block
// token sharing.
// ---------------------------------------------------------------------------
__global__ __launch_bounds__(256) void out_kernel(
    const ushortT* __restrict__ qn, const ushortT* __restrict__ kn,
    const float* __restrict__ g_k, const float* __restrict__ Wr,
    const float* __restrict__ br, float* __restrict__ out)
{
    __shared__ float kvi[16 * 512];
    __shared__ float gks[512];
    const int tid = threadIdx.x;
    const size_t tok0 = (size_t)blockIdx.x * 16;
    const int b = (int)(tok0 >> 12);

    gks[tid] = g_k[b * DD + tid];
    gks[256 + tid] = g_k[b * DD + 256 + tid];
    __syncthreads();

    // build kvi tile in fp32 LDS (reads kn from the d_out alias)
    #pragma unroll
    for (int it = 0; it < 4; ++it) {
        int idx = it * 2048 + tid * 8;
        int col = idx & 511;
        uint4 qv = *reinterpret_cast<const uint4*>(qn + tok0 * DD + idx);
        uint4 kv = *reinterpret_cast<const uint4*>(kn + tok0 * DD + idx);
        kvi[idx + 0] = fmaf(gks[col + 0], bf_lo(kv.x), bf_lo(qv.x));
        kvi[idx + 1] = fmaf(gks[col + 1], bf_hi(kv.x), bf_hi(qv.x));
        kvi[idx + 2] = fmaf(gks[col + 2], bf_lo(kv.y), bf_lo(qv.y));
        kvi[idx + 3] = fmaf(gks[col + 3], bf_hi(kv.y), bf_hi(qv.y));
        kvi[idx + 4] = fmaf(gks[col + 4], bf_lo(kv.z), bf_lo(qv.z));
        kvi[idx + 5] = fmaf(gks[col + 5], bf_hi(kv.z), bf_hi(qv.z));
        kvi[idx + 6] = fmaf(gks[col + 6], bf_lo(kv.w), bf_lo(qv.w));
        kvi[idx + 7] = fmaf(gks[col + 7], bf_hi(kv.w), bf_hi(qv.w));
    }
    __syncthreads();

    const int lane = tid & 63, w = tid >> 6;
    const int j0 = lane * 4;
    const int t0 = w * 4;
    float acc[4][4];
    #pragma unroll
    for (int t = 0; t < 4; ++t)
        for (int c = 0; c < 4; ++c) acc[t][c] = 0.f;

    for (int i = 0; i < 512; i += 2) {
        float4 w0 = *reinterpret_cast<const float4*>(Wr + (size_t)i * TD + j0);
        float4 w1 = *reinterpret_cast<const float4*>(Wr + (size_t)(i + 1) * TD + j0);
        #pragma unroll
        for (int tt = 0; tt < 4; ++tt) {
            float2 xv = *reinterpret_cast<const float2*>(&kvi[(t0 + tt) * 512 + i]); // broadcast
            acc[tt][0] = fmaf(xv.y, w1.x, fmaf(xv.x, w0.x, acc[tt][0]));
            acc[tt][1] = fmaf(xv.y, w1.y, fmaf(xv.x, w0.y, acc[tt][1]));
            acc[tt][2] = fmaf(xv.y, w1.z, fmaf(xv.x, w0.z, acc[tt][2]));
            acc[tt][3] = fmaf(xv.y, w1.w, fmaf(xv.x, w0.w, acc[tt][3]));
        }
    }

    float b0 = br[j0], b1 = br[j0 + 1], b2 = br[j0 + 2], b3 = br[j0 + 3];
    #pragma unroll
    for (int tt = 0; tt < 4; ++tt) {
        float4 st;
        st.x = acc[tt][0] + b0;
        st.y = acc[tt][1] + b1;
        st.z = acc[tt][2] + b2;
        st.w = acc[tt][3] + b3;
        *reinterpret_cast<float4*>(out + (tok0 + t0 + tt) * TD + j0) = st;
    }
}

// ---------------------------------------------------------------------------
extern "C" void kernel_launch(void* const* d_in, const int* in_sizes, int n_in,
                              void* d_out, int out_size, void* d_ws, size_t ws_size,
                              hipStream_t stream)
{
    const float* x       = (const float*)d_in[0];
    const float* Wq      = (const float*)d_in[1];
    const float* bq      = (const float*)d_in[2];
    const float* Wk      = (const float*)d_in[3];
    const float* bk      = (const float*)d_in[4];
    const float* Wr      = (const float*)d_in[5];
    const float* br      = (const float*)d_in[6];
    const float* w_alpha = (const float*)d_in[7];
    const float* w_beta  = (const float*)d_in[8];
    float* out = (float*)d_out;

    // kn ALIASES d_out: both are exactly NTOK*1024 bytes, token-t byte ranges
    // coincide. Keeps total d_ws usage at ~33.9 MB (round-3 layout used 67.4 MB
    // and overflowed the workspace, corrupting neighboring allocations).
    ushortT* kn = (ushortT*)d_out;

    char* ws = (char*)d_ws;
    ushortT* qn = (ushortT*)ws;        ws += (size_t)NTOK * DD * sizeof(ushortT);   // 32 MiB
    float* alpha_raw = (float*)ws;     ws += (size_t)NTOK * sizeof(float);
    float* beta_raw  = (float*)ws;     ws += (size_t)NTOK * sizeof(float);
    float* gq_raw = (float*)ws;        ws += (size_t)BATCH * DD * sizeof(float);
    float* h_raw  = (float*)ws;        ws += (size_t)BATCH * DD * sizeof(float);  // contiguous w/ gq_raw
    float* g_q    = (float*)ws;        ws += (size_t)BATCH * DD * sizeof(float);
    float* wb2    = (float*)ws;        ws += (size_t)BATCH * DD * sizeof(float);
    float* g_k    = (float*)ws;        ws += (size_t)BATCH * DD * sizeof(float);
    float* inv_a  = (float*)ws;        ws += 64;
    float* inv_b  = (float*)ws;        ws += 64;

    // zero the two atomic accumulators (gq_raw + h_raw are adjacent)
    hipMemsetAsync(gq_raw, 0, 2 * BATCH * DD * sizeof(float), stream);

    qk_kernel<<<NTOK / 16, 256, 0, stream>>>(x, Wq, bq, Wk, bk, w_alpha, qn, kn, alpha_raw);
    norm_kernel<<<BATCH, 256, 0, stream>>>(alpha_raw, inv_a);
    wsum_kernel<<<256, 256, 0, stream>>>(qn, alpha_raw, inv_a, gq_raw);
    softmax_kernel<<<BATCH, 256, 0, stream>>>(gq_raw, nullptr, w_beta, g_q, wb2);
    beta_kernel<<<NTOK / 4, 256, 0, stream>>>(kn, wb2, beta_raw);
    norm_kernel<<<BATCH, 256, 0, stream>>>(beta_raw, inv_b);
    wsum_kernel<<<256, 256, 0, stream>>>(kn, beta_raw, inv_b, h_raw);
    softmax_kernel<<<BATCH, 256, 0, stream>>>(h_raw, g_q, nullptr, g_k, nullptr);
    out_kernel<<<NTOK / 16, 256, 0, stream>>>(qn, kn, g_k, Wr, br, out);
}

// Round 6
// 409.727 us; speedup vs baseline: 1.7000x; 1.7000x over previous
//
#include <hip/hip_runtime.h>
#include <hip/hip_bf16.h>
#include <stdint.h>

// Problem constants (fixed by setup_inputs)
#define BATCH    8
#define NTOKB    4096                 // tokens per batch
#define NTOK     (BATCH * NTOKB)     // 32768
#define DIN      512
#define DD       512                 // TOKEN_DIM * NUM_HEADS
#define TD       256                 // TOKEN_DIM
#define SCALE    0.0625f             // 256^-0.5

typedef unsigned short ushortT;
typedef __attribute__((ext_vector_type(8))) short  short8;   // 8 bf16 = 4 VGPR
typedef __attribute__((ext_vector_type(4))) float  f32x4;

__device__ __forceinline__ float bf_lo(uint32_t u) { return __uint_as_float(u << 16); }
__device__ __forceinline__ float bf_hi(uint32_t u) { return __uint_as_float(u & 0xffff0000u); }
__device__ __forceinline__ float bf2f(ushortT u) { return __uint_as_float(((uint32_t)u) << 16); }
// round-to-nearest-even f32 -> bf16
__device__ __forceinline__ ushortT f2bf(float f) {
    uint32_t u = __float_as_uint(f);
    return (ushortT)((u + 0x7fffu + ((u >> 16) & 1u)) >> 16);
}

// ---------------------------------------------------------------------------
// K0: pack Wq/Wk fp32 [k512][n512] -> bf16 chunk-tiled [mat][c16][n512][k32]
// grid = 32 blocks (mat*16 + chunk), 256 threads. Reads coalesced (n fastest).
// ---------------------------------------------------------------------------
__global__ __launch_bounds__(256) void packw_kernel(
    const float* __restrict__ Wq, const float* __restrict__ Wk,
    ushortT* __restrict__ W16)
{
    const int mat = blockIdx.x >> 4, c = blockIdx.x & 15;
    const float* S = mat ? Wk : Wq;
    ushortT* D = W16 + (size_t)mat * (512 * 512) + (size_t)c * 16384;
    for (int i = threadIdx.x; i < 16384; i += 256) {
        int n = i & 511, kk = i >> 9;                 // read: consecutive n -> coalesced
        D[n * 32 + kk] = f2bf(S[(size_t)(c * 32 + kk) * 512 + n]);
    }
}

// ---------------------------------------------------------------------------
// K6: MFMA GEMM: raw = x @ W + bias, written bf16 (UNNORMALIZED).
// Block = 512 thr (8 waves): 64 tokens x 512 cols of ONE matrix (y=0 q, y=1 k).
// Wave = 64x64 (4x4 tiles of 16x16x32). K=512 staged in 16 chunks of 32.
// ONE mfma_f32_16x16x32_bf16 consumes the full K=32 chunk: lane fragment is
// A[m=lane&15][k=quad*8+j] (j=0..7), B[n=lane&15][k=quad*8+j] from B^T LDS.
// (Round-5 bug: treated it as 2 x K16 steps -> double-count + OOB LDS read.)
// D layout: col=lane&15, row=quad*4+reg (verified m89/m91).
// ---------------------------------------------------------------------------
__global__ __launch_bounds__(512) void gemm_qk_kernel(
    const float* __restrict__ x, const ushortT* __restrict__ W16,
    const float* __restrict__ bq, const float* __restrict__ bk,
    ushortT* __restrict__ qn, ushortT* __restrict__ kn)
{
    __shared__ ushortT xs[64 * 32];      // x tile  [tok][k]  4 KB
    __shared__ ushortT wsd[512 * 32];    // W tile  [n][k]   32 KB

    const int tid = threadIdx.x;
    const int mat = blockIdx.y;
    const size_t tok0 = (size_t)blockIdx.x * 64;
    const ushortT* Wb = W16 + (size_t)mat * (512 * 512);
    const float* bias = mat ? bk : bq;
    ushortT* dst = mat ? kn : qn;

    const int lane = tid & 63, w = tid >> 6;    // 8 waves: wave w -> cols [w*64, w*64+64)
    const int m = lane & 15, quad = lane >> 4;

    f32x4 acc[4][4];
    #pragma unroll
    for (int tr = 0; tr < 4; ++tr)
        #pragma unroll
        for (int tc = 0; tc < 4; ++tc) acc[tr][tc] = (f32x4){0.f, 0.f, 0.f, 0.f};

    // staging assignments (chunk-invariant)
    const int xtok = tid >> 3;                 // 0..63
    const int xkg  = (tid & 7) * 4;            // 0..28
    const float* xsrc = x + (tok0 + xtok) * DIN;

    for (int c = 0; c < 16; ++c) {
        __syncthreads();   // previous chunk's compute done before LDS overwrite
        // ---- stage x: 64 tok x 32 k, fp32 -> bf16
        {
            float4 xv = *reinterpret_cast<const float4*>(xsrc + c * 32 + xkg);
            ushort4 xb;
            xb.x = f2bf(xv.x); xb.y = f2bf(xv.y); xb.z = f2bf(xv.z); xb.w = f2bf(xv.w);
            *reinterpret_cast<ushort4*>(&xs[xtok * 32 + xkg]) = xb;
        }
        // ---- stage W chunk: 512 n x 32 k bf16 (already packed [n][k])
        {
            const uint4* gw = reinterpret_cast<const uint4*>(Wb + (size_t)c * 16384 + tid * 32);
            uint4* lw = reinterpret_cast<uint4*>(&wsd[tid * 32]);
            #pragma unroll
            for (int i = 0; i < 4; ++i) lw[i] = gw[i];
        }
        __syncthreads();
        // ---- compute: one K=32 MFMA per (tr,tc); lane fragment at quad*8
        {
            short8 af[4], bf[4];
            #pragma unroll
            for (int tr = 0; tr < 4; ++tr)
                af[tr] = *reinterpret_cast<const short8*>(&xs[(tr * 16 + m) * 32 + quad * 8]);
            #pragma unroll
            for (int tc = 0; tc < 4; ++tc)
                bf[tc] = *reinterpret_cast<const short8*>(&wsd[(w * 64 + tc * 16 + m) * 32 + quad * 8]);
            #pragma unroll
            for (int tr = 0; tr < 4; ++tr)
                #pragma unroll
                for (int tc = 0; tc < 4; ++tc)
                    acc[tr][tc] = __builtin_amdgcn_mfma_f32_16x16x32_bf16(af[tr], bf[tc], acc[tr][tc], 0, 0, 0);
        }
    }

    // ---- epilogue: + bias, store bf16 raw (normalized later in-place)
    float biasv[4];
    #pragma unroll
    for (int tc = 0; tc < 4; ++tc) biasv[tc] = bias[w * 64 + tc * 16 + m];
    #pragma unroll
    for (int tr = 0; tr < 4; ++tr) {
        #pragma unroll
        for (int reg = 0; reg < 4; ++reg) {
            size_t row = tok0 + tr * 16 + quad * 4 + reg;
            ushortT* rp = dst + row * DD + w * 64 + m;
            #pragma unroll
            for (int tc = 0; tc < 4; ++tc)
                rp[tc * 16] = f2bf(acc[tr][tc][reg] + biasv[tc]);
        }
    }
}

// ---------------------------------------------------------------------------
// K7: in-place l2norm of qn and kn rows (bf16) + alpha_raw from normalized q.
// One wave per token; lane covers cols [lane*8, lane*8+8).
// ---------------------------------------------------------------------------
__global__ __launch_bounds__(256) void normalize_kernel(
    ushortT* __restrict__ qn, ushortT* __restrict__ kn,
    const float* __restrict__ w_alpha, float* __restrict__ alpha_raw)
{
    const int tid = threadIdx.x, lane = tid & 63, wv = tid >> 6;
    const size_t t = (size_t)blockIdx.x * 4 + wv;

    // ---- q row
    {
        uint4 v = *reinterpret_cast<const uint4*>(qn + t * DD + lane * 8);
        float f0 = bf_lo(v.x), f1 = bf_hi(v.x), f2 = bf_lo(v.y), f3 = bf_hi(v.y);
        float f4 = bf_lo(v.z), f5 = bf_hi(v.z), f6 = bf_lo(v.w), f7 = bf_hi(v.w);
        float ss = f0*f0 + f1*f1 + f2*f2 + f3*f3 + f4*f4 + f5*f5 + f6*f6 + f7*f7;
        #pragma unroll
        for (int off = 32; off > 0; off >>= 1) ss += __shfl_xor(ss, off);
        float r = 1.0f / fmaxf(sqrtf(ss), 1e-12f);
        f0 *= r; f1 *= r; f2 *= r; f3 *= r; f4 *= r; f5 *= r; f6 *= r; f7 *= r;
        ushort4 st;
        st.x = f2bf(f0); st.y = f2bf(f1); st.z = f2bf(f2); st.w = f2bf(f3);
        ushort4 st2;
        st2.x = f2bf(f4); st2.y = f2bf(f5); st2.z = f2bf(f6); st2.w = f2bf(f7);
        uint4 sv;
        sv.x = ((uint32_t)st.y  << 16) | st.x;  sv.y = ((uint32_t)st.w  << 16) | st.z;
        sv.z = ((uint32_t)st2.y << 16) | st2.x; sv.w = ((uint32_t)st2.w << 16) | st2.z;
        *reinterpret_cast<uint4*>(qn + t * DD + lane * 8) = sv;
        // alpha partial (uses bf16-rounded normalized values, matches later readers)
        float4 wa0 = *reinterpret_cast<const float4*>(w_alpha + lane * 8);
        float4 wa1 = *reinterpret_cast<const float4*>(w_alpha + lane * 8 + 4);
        float al = bf2f(st.x)*wa0.x + bf2f(st.y)*wa0.y + bf2f(st.z)*wa0.z + bf2f(st.w)*wa0.w
                 + bf2f(st2.x)*wa1.x + bf2f(st2.y)*wa1.y + bf2f(st2.z)*wa1.z + bf2f(st2.w)*wa1.w;
        #pragma unroll
        for (int off = 32; off > 0; off >>= 1) al += __shfl_xor(al, off);
        if (lane == 0) alpha_raw[t] = SCALE * al;
    }
    // ---- k row
    {
        uint4 v = *reinterpret_cast<const uint4*>(kn + t * DD + lane * 8);
        float f0 = bf_lo(v.x), f1 = bf_hi(v.x), f2 = bf_lo(v.y), f3 = bf_hi(v.y);
        float f4 = bf_lo(v.z), f5 = bf_hi(v.z), f6 = bf_lo(v.w), f7 = bf_hi(v.w);
        float ss = f0*f0 + f1*f1 + f2*f2 + f3*f3 + f4*f4 + f5*f5 + f6*f6 + f7*f7;
        #pragma unroll
        for (int off = 32; off > 0; off >>= 1) ss += __shfl_xor(ss, off);
        float r = 1.0f / fmaxf(sqrtf(ss), 1e-12f);
        f0 *= r; f1 *= r; f2 *= r; f3 *= r; f4 *= r; f5 *= r; f6 *= r; f7 *= r;
        uint4 sv;
        sv.x = ((uint32_t)f2bf(f1) << 16) | f2bf(f0);
        sv.y = ((uint32_t)f2bf(f3) << 16) | f2bf(f2);
        sv.z = ((uint32_t)f2bf(f5) << 16) | f2bf(f4);
        sv.w = ((uint32_t)f2bf(f7) << 16) | f2bf(f6);
        *reinterpret_cast<uint4*>(kn + t * DD + lane * 8) = sv;
    }
}

// ---------------------------------------------------------------------------
// K2: per-batch inverse L2 norm of a [4096] vector
// ---------------------------------------------------------------------------
__global__ __launch_bounds__(256) void norm_kernel(const float* __restrict__ in,
                                                   float* __restrict__ inv_out)
{
    int b = blockIdx.x;
    __shared__ float red[256];
    float s = 0.f;
    for (int i = threadIdx.x; i < NTOKB; i += 256) {
        float v = in[b * NTOKB + i];
        s = fmaf(v, v, s);
    }
    red[threadIdx.x] = s;
    __syncthreads();
    for (int off = 128; off > 0; off >>= 1) {
        if (threadIdx.x < off) red[threadIdx.x] += red[threadIdx.x + off];
        __syncthreads();
    }
    if (threadIdx.x == 0) inv_out[b] = 1.0f / fmaxf(sqrtf(red[0]), 1e-12f);
}

// ---------------------------------------------------------------------------
// K3: dst[b,d] += sum_i raw[b,i]*inv[b] * M[b,i,d]   (fp32 atomics; dst pre-zeroed)
// grid = 256 blocks: b(8) x colchunk(2) x iseg(16); M is bf16
// ---------------------------------------------------------------------------
__global__ __launch_bounds__(256) void wsum_kernel(const ushortT* __restrict__ M,
                                                   const float* __restrict__ raw,
                                                   const float* __restrict__ invp,
                                                   float* __restrict__ dst)
{
    int blk = blockIdx.x;
    int b = blk >> 5;
    int r = blk & 31;
    int d0 = (r >> 4) * 256 + threadIdx.x;
    int i0 = (r & 15) * 256;
    const size_t rowbase = (size_t)b * NTOKB + i0;
    float acc = 0.f;
    for (int ii = 0; ii < 256; ++ii) {
        float w = raw[rowbase + ii];
        acc = fmaf(w, bf2f(M[(rowbase + ii) * DD + d0]), acc);
    }
    atomicAdd(&dst[b * DD + d0], acc * invp[b]);
}

// ---------------------------------------------------------------------------
// K4: per-batch softmax over 512; optional elementwise premultiplier and
// optional wb2 = softmax * w_beta output.
// ---------------------------------------------------------------------------
__global__ __launch_bounds__(256) void softmax_kernel(const float* __restrict__ in,
                                                      const float* __restrict__ mul,
                                                      const float* __restrict__ wbeta,
                                                      float* __restrict__ out,
                                                      float* __restrict__ wb2)
{
    int b = blockIdx.x, tid = threadIdx.x;
    __shared__ float red[256];
    float v0 = in[b * DD + tid], v1 = in[b * DD + 256 + tid];
    if (mul) { v0 *= mul[b * DD + tid]; v1 *= mul[b * DD + 256 + tid]; }
    red[tid] = fmaxf(v0, v1);
    __syncthreads();
    for (int off = 128; off > 0; off >>= 1) {
        if (tid < off) red[tid] = fmaxf(red[tid], red[tid + off]);
        __syncthreads();
    }
    float m = red[0];
    __syncthreads();
    float e0 = expf(v0 - m), e1 = expf(v1 - m);
    red[tid] = e0 + e1;
    __syncthreads();
    for (int off = 128; off > 0; off >>= 1) {
        if (tid < off) red[tid] += red[tid + off];
        __syncthreads();
    }
    float rs = 1.0f / red[0];
    float o0 = e0 * rs, o1 = e1 * rs;
    out[b * DD + tid] = o0;
    out[b * DD + 256 + tid] = o1;
    if (wb2) {
        wb2[b * DD + tid]       = o0 * wbeta[tid];
        wb2[b * DD + 256 + tid] = o1 * wbeta[256 + tid];
    }
}

// ---------------------------------------------------------------------------
// K5: beta_raw[tok] = SCALE * dot(kn[tok,:], wb2[b,:])  — one wave per token
// ---------------------------------------------------------------------------
__global__ __launch_bounds__(256) void beta_kernel(const ushortT* __restrict__ kn,
                                                   const float* __restrict__ wb2,
                                                   float* __restrict__ beta_raw)
{
    int wave = threadIdx.x >> 6, lane = threadIdx.x & 63;
    size_t tok = (size_t)blockIdx.x * 4 + wave;
    int b = (int)(tok >> 12);
    uint4 kv = *reinterpret_cast<const uint4*>(kn + tok * DD + lane * 8);
    float4 wv0 = *reinterpret_cast<const float4*>(wb2 + b * DD + lane * 8);
    float4 wv1 = *reinterpret_cast<const float4*>(wb2 + b * DD + lane * 8 + 4);
    float s = bf_lo(kv.x) * wv0.x + bf_hi(kv.x) * wv0.y
            + bf_lo(kv.y) * wv0.z + bf_hi(kv.y) * wv0.w
            + bf_lo(kv.z) * wv1.x + bf_hi(kv.z) * wv1.y
            + bf_lo(kv.w) * wv1.z + bf_hi(kv.w) * wv1.w;
    #pragma unroll
    for (int off = 32; off > 0; off >>= 1) s += __shfl_xor(s, off);
    if (lane == 0) beta_raw[tok] = SCALE * s;
}

// ---------------------------------------------------------------------------
// K8: out = (g_k*kn + qn) @ Wr + br, per 16-token tile. Output fp32.
// NOTE: kn ALIASES d_out (token t = bytes [t*1024, t*1024+1024) in both).
// Safe: each block stages its own 16-token kn range into LDS (+barrier)
// before the epilogue overwrites exactly that byte range.
// ---------------------------------------------------------------------------
__global__ __launch_bounds__(256) void out_kernel(
    const ushortT* __restrict__ qn, const ushortT* __restrict__ kn,
    const float* __restrict__ g_k, const float* __restrict__ Wr,
    const float* __restrict__ br, float* __restrict__ out)
{
    __shared__ float kvi[16 * 512];
    __shared__ float gks[512];
    const int tid = threadIdx.x;
    const size_t tok0 = (size_t)blockIdx.x * 16;
    const int b = (int)(tok0 >> 12);

    gks[tid] = g_k[b * DD + tid];
    gks[256 + tid] = g_k[b * DD + 256 + tid];
    __syncthreads();

    #pragma unroll
    for (int it = 0; it < 4; ++it) {
        int idx = it * 2048 + tid * 8;
        int col = idx & 511;
        uint4 qv = *reinterpret_cast<const uint4*>(qn + tok0 * DD + idx);
        uint4 kv = *reinterpret_cast<const uint4*>(kn + tok0 * DD + idx);
        kvi[idx + 0] = fmaf(gks[col + 0], bf_lo(kv.x), bf_lo(qv.x));
        kvi[idx + 1] = fmaf(gks[col + 1], bf_hi(kv.x), bf_hi(qv.x));
        kvi[idx + 2] = fmaf(gks[col + 2], bf_lo(kv.y), bf_lo(qv.y));
        kvi[idx + 3] = fmaf(gks[col + 3], bf_hi(kv.y), bf_hi(qv.y));
        kvi[idx + 4] = fmaf(gks[col + 4], bf_lo(kv.z), bf_lo(qv.z));
        kvi[idx + 5] = fmaf(gks[col + 5], bf_hi(kv.z), bf_hi(qv.z));
        kvi[idx + 6] = fmaf(gks[col + 6], bf_lo(kv.w), bf_lo(qv.w));
        kvi[idx + 7] = fmaf(gks[col + 7], bf_hi(kv.w), bf_hi(qv.w));
    }
    __syncthreads();

    const int lane = tid & 63, w = tid >> 6;
    const int j0 = lane * 4;
    const int t0 = w * 4;
    float acc[4][4];
    #pragma unroll
    for (int t = 0; t < 4; ++t)
        for (int c = 0; c < 4; ++c) acc[t][c] = 0.f;

    for (int i = 0; i < 512; i += 2) {
        float4 w0 = *reinterpret_cast<const float4*>(Wr + (size_t)i * TD + j0);
        float4 w1 = *reinterpret_cast<const float4*>(Wr + (size_t)(i + 1) * TD + j0);
        #pragma unroll
        for (int tt = 0; tt < 4; ++tt) {
            float2 xv = *reinterpret_cast<const float2*>(&kvi[(t0 + tt) * 512 + i]); // broadcast
            acc[tt][0] = fmaf(xv.y, w1.x, fmaf(xv.x, w0.x, acc[tt][0]));
            acc[tt][1] = fmaf(xv.y, w1.y, fmaf(xv.x, w0.y, acc[tt][1]));
            acc[tt][2] = fmaf(xv.y, w1.z, fmaf(xv.x, w0.z, acc[tt][2]));
            acc[tt][3] = fmaf(xv.y, w1.w, fmaf(xv.x, w0.w, acc[tt][3]));
        }
    }

    float b0 = br[j0], b1 = br[j0 + 1], b2 = br[j0 + 2], b3 = br[j0 + 3];
    #pragma unroll
    for (int tt = 0; tt < 4; ++tt) {
        float4 st;
        st.x = acc[tt][0] + b0;
        st.y = acc[tt][1] + b1;
        st.z = acc[tt][2] + b2;
        st.w = acc[tt][3] + b3;
        *reinterpret_cast<float4*>(out + (tok0 + t0 + tt) * TD + j0) = st;
    }
}

// ---------------------------------------------------------------------------
extern "C" void kernel_launch(void* const* d_in, const int* in_sizes, int n_in,
                              void* d_out, int out_size, void* d_ws, size_t ws_size,
                              hipStream_t stream)
{
    const float* x       = (const float*)d_in[0];
    const float* Wq      = (const float*)d_in[1];
    const float* bq      = (const float*)d_in[2];
    const float* Wk      = (const float*)d_in[3];
    const float* bk      = (const float*)d_in[4];
    const float* Wr      = (const float*)d_in[5];
    const float* br      = (const float*)d_in[6];
    const float* w_alpha = (const float*)d_in[7];
    const float* w_beta  = (const float*)d_in[8];
    float* out = (float*)d_out;

    // kn ALIASES d_out (byte-identical token ranges); total ws ~34.9 MB.
    ushortT* kn = (ushortT*)d_out;

    char* ws = (char*)d_ws;
    ushortT* qn = (ushortT*)ws;        ws += (size_t)NTOK * DD * sizeof(ushortT);   // 32 MiB
    ushortT* W16 = (ushortT*)ws;       ws += (size_t)2 * 512 * 512 * sizeof(ushortT); // 1 MiB
    float* alpha_raw = (float*)ws;     ws += (size_t)NTOK * sizeof(float);
    float* beta_raw  = (float*)ws;     ws += (size_t)NTOK * sizeof(float);
    float* gq_raw = (float*)ws;        ws += (size_t)BATCH * DD * sizeof(float);
    float* h_raw  = (float*)ws;        ws += (size_t)BATCH * DD * sizeof(float);  // contiguous w/ gq_raw
    float* g_q    = (float*)ws;        ws += (size_t)BATCH * DD * sizeof(float);
    float* wb2    = (float*)ws;        ws += (size_t)BATCH * DD * sizeof(float);
    float* g_k    = (float*)ws;        ws += (size_t)BATCH * DD * sizeof(float);
    float* inv_a  = (float*)ws;        ws += 64;
    float* inv_b  = (float*)ws;        ws += 64;

    hipMemsetAsync(gq_raw, 0, 2 * BATCH * DD * sizeof(float), stream);

    packw_kernel<<<32, 256, 0, stream>>>(Wq, Wk, W16);
    gemm_qk_kernel<<<dim3(NTOK / 64, 2), 512, 0, stream>>>(x, W16, bq, bk, qn, kn);
    normalize_kernel<<<NTOK / 4, 256, 0, stream>>>(qn, kn, w_alpha, alpha_raw);
    norm_kernel<<<BATCH, 256, 0, stream>>>(alpha_raw, inv_a);
    wsum_kernel<<<256, 256, 0, stream>>>(qn, alpha_raw, inv_a, gq_raw);
    softmax_kernel<<<BATCH, 256, 0, stream>>>(gq_raw, nullptr, w_beta, g_q, wb2);
    beta_kernel<<<NTOK / 4, 256, 0, stream>>>(kn, wb2, beta_raw);
    norm_kernel<<<BATCH, 256, 0, stream>>>(beta_raw, inv_b);
    wsum_kernel<<<256, 256, 0, stream>>>(kn, beta_raw, inv_b, h_raw);
    softmax_kernel<<<BATCH, 256, 0, stream>>>(h_raw, g_q, nullptr, g_k, nullptr);
    out_kernel<<<NTOK / 16, 256, 0, stream>>>(qn, kn, g_k, Wr, br, out);
}

// Round 7
// 284.874 us; speedup vs baseline: 2.4451x; 1.4383x over previous
//
#include <hip/hip_runtime.h>
#include <hip/hip_bf16.h>
#include <stdint.h>

// Problem constants (fixed by setup_inputs)
#define BATCH    8
#define NTOKB    4096                 // tokens per batch
#define NTOK     (BATCH * NTOKB)     // 32768
#define DIN      512
#define DD       512                 // TOKEN_DIM * NUM_HEADS
#define TD       256                 // TOKEN_DIM
#define SCALE    0.0625f             // 256^-0.5

typedef unsigned short ushortT;
typedef __attribute__((ext_vector_type(8))) short  short8;   // 8 bf16 = 4 VGPR
typedef __attribute__((ext_vector_type(4))) float  f32x4;

__device__ __forceinline__ float bf_lo(uint32_t u) { return __uint_as_float(u << 16); }
__device__ __forceinline__ float bf_hi(uint32_t u) { return __uint_as_float(u & 0xffff0000u); }
__device__ __forceinline__ float bf2f(ushortT u) { return __uint_as_float(((uint32_t)u) << 16); }
// round-to-nearest-even f32 -> bf16
__device__ __forceinline__ ushortT f2bf(float f) {
    uint32_t u = __float_as_uint(f);
    return (ushortT)((u + 0x7fffu + ((u >> 16) & 1u)) >> 16);
}

// ---------------------------------------------------------------------------
// K0: pack weights fp32 -> bf16 chunk-tiled B^T form [chunk][n][k32].
// blocks 0..15: Wq, 16..31: Wk (n=512), 32..47: Wr (n=256).
// ---------------------------------------------------------------------------
__global__ __launch_bounds__(256) void packw_kernel(
    const float* __restrict__ Wq, const float* __restrict__ Wk,
    const float* __restrict__ Wr, ushortT* __restrict__ W16)
{
    const int blk = blockIdx.x;
    if (blk < 32) {
        const int mat = blk >> 4, c = blk & 15;
        const float* S = mat ? Wk : Wq;
        ushortT* D = W16 + (size_t)mat * (512 * 512) + (size_t)c * 16384;
        for (int i = threadIdx.x; i < 16384; i += 256) {
            int n = i & 511, kk = i >> 9;             // consecutive n -> coalesced read
            D[n * 32 + kk] = f2bf(S[(size_t)(c * 32 + kk) * 512 + n]);
        }
    } else {
        const int c = blk - 32;
        ushortT* D = W16 + (size_t)2 * (512 * 512) + (size_t)c * 8192;
        for (int i = threadIdx.x; i < 8192; i += 256) {
            int n = i & 255, kk = i >> 8;
            D[n * 32 + kk] = f2bf(Wr[(size_t)(c * 32 + kk) * 256 + n]);
        }
    }
}

// ---------------------------------------------------------------------------
// K6: MFMA GEMM: raw = x @ W + bias, written bf16 (UNNORMALIZED).
// Block = 512 thr (8 waves): 64 tokens x 512 cols of ONE matrix (y=0 q, y=1 k).
// Wave = 64x64 (4x4 tiles of 16x16x32). K=512 staged in 16 chunks of 32.
// Lane fragments: A[m=lane&15][k=quad*8+j], B[n=lane&15][k=quad*8+j] (B^T LDS);
// D: col=lane&15, row=quad*4+reg (verified m89/m91).
// ---------------------------------------------------------------------------
__global__ __launch_bounds__(512) void gemm_qk_kernel(
    const float* __restrict__ x, const ushortT* __restrict__ W16,
    const float* __restrict__ bq, const float* __restrict__ bk,
    ushortT* __restrict__ qn, ushortT* __restrict__ kn)
{
    __shared__ ushortT xs[64 * 32];      // x tile  [tok][k]  4 KB
    __shared__ ushortT wsd[512 * 32];    // W tile  [n][k]   32 KB

    const int tid = threadIdx.x;
    const int mat = blockIdx.y;
    const size_t tok0 = (size_t)blockIdx.x * 64;
    const ushortT* Wb = W16 + (size_t)mat * (512 * 512);
    const float* bias = mat ? bk : bq;
    ushortT* dst = mat ? kn : qn;

    const int lane = tid & 63, w = tid >> 6;    // wave w -> cols [w*64, w*64+64)
    const int m = lane & 15, quad = lane >> 4;

    f32x4 acc[4][4];
    #pragma unroll
    for (int tr = 0; tr < 4; ++tr)
        #pragma unroll
        for (int tc = 0; tc < 4; ++tc) acc[tr][tc] = (f32x4){0.f, 0.f, 0.f, 0.f};

    const int xtok = tid >> 3;                 // 0..63
    const int xkg  = (tid & 7) * 4;            // 0..28
    const float* xsrc = x + (tok0 + xtok) * DIN;

    for (int c = 0; c < 16; ++c) {
        __syncthreads();
        // ---- stage x: 64 tok x 32 k, fp32 -> bf16
        {
            float4 xv = *reinterpret_cast<const float4*>(xsrc + c * 32 + xkg);
            ushort4 xb;
            xb.x = f2bf(xv.x); xb.y = f2bf(xv.y); xb.z = f2bf(xv.z); xb.w = f2bf(xv.w);
            *reinterpret_cast<ushort4*>(&xs[xtok * 32 + xkg]) = xb;
        }
        // ---- stage W chunk: 512 n x 32 k bf16
        {
            const uint4* gw = reinterpret_cast<const uint4*>(Wb + (size_t)c * 16384 + tid * 32);
            uint4* lw = reinterpret_cast<uint4*>(&wsd[tid * 32]);
            #pragma unroll
            for (int i = 0; i < 4; ++i) lw[i] = gw[i];
        }
        __syncthreads();
        // ---- compute: one K=32 MFMA per (tr,tc)
        {
            short8 af[4], bf[4];
            #pragma unroll
            for (int tr = 0; tr < 4; ++tr)
                af[tr] = *reinterpret_cast<const short8*>(&xs[(tr * 16 + m) * 32 + quad * 8]);
            #pragma unroll
            for (int tc = 0; tc < 4; ++tc)
                bf[tc] = *reinterpret_cast<const short8*>(&wsd[(w * 64 + tc * 16 + m) * 32 + quad * 8]);
            #pragma unroll
            for (int tr = 0; tr < 4; ++tr)
                #pragma unroll
                for (int tc = 0; tc < 4; ++tc)
                    acc[tr][tc] = __builtin_amdgcn_mfma_f32_16x16x32_bf16(af[tr], bf[tc], acc[tr][tc], 0, 0, 0);
        }
    }

    // ---- epilogue: + bias, store bf16 raw (normalized later in-place)
    float biasv[4];
    #pragma unroll
    for (int tc = 0; tc < 4; ++tc) biasv[tc] = bias[w * 64 + tc * 16 + m];
    #pragma unroll
    for (int tr = 0; tr < 4; ++tr) {
        #pragma unroll
        for (int reg = 0; reg < 4; ++reg) {
            size_t row = tok0 + tr * 16 + quad * 4 + reg;
            ushortT* rp = dst + row * DD + w * 64 + m;
            #pragma unroll
            for (int tc = 0; tc < 4; ++tc)
                rp[tc * 16] = f2bf(acc[tr][tc][reg] + biasv[tc]);
        }
    }
}

// ---------------------------------------------------------------------------
// K7: in-place l2norm of qn and kn rows (bf16) + alpha_raw from normalized q.
// ---------------------------------------------------------------------------
__global__ __launch_bounds__(256) void normalize_kernel(
    ushortT* __restrict__ qn, ushortT* __restrict__ kn,
    const float* __restrict__ w_alpha, float* __restrict__ alpha_raw)
{
    const int tid = threadIdx.x, lane = tid & 63, wv = tid >> 6;
    const size_t t = (size_t)blockIdx.x * 4 + wv;

    // ---- q row
    {
        uint4 v = *reinterpret_cast<const uint4*>(qn + t * DD + lane * 8);
        float f0 = bf_lo(v.x), f1 = bf_hi(v.x), f2 = bf_lo(v.y), f3 = bf_hi(v.y);
        float f4 = bf_lo(v.z), f5 = bf_hi(v.z), f6 = bf_lo(v.w), f7 = bf_hi(v.w);
        float ss = f0*f0 + f1*f1 + f2*f2 + f3*f3 + f4*f4 + f5*f5 + f6*f6 + f7*f7;
        #pragma unroll
        for (int off = 32; off > 0; off >>= 1) ss += __shfl_xor(ss, off);
        float r = 1.0f / fmaxf(sqrtf(ss), 1e-12f);
        f0 *= r; f1 *= r; f2 *= r; f3 *= r; f4 *= r; f5 *= r; f6 *= r; f7 *= r;
        ushort4 st;
        st.x = f2bf(f0); st.y = f2bf(f1); st.z = f2bf(f2); st.w = f2bf(f3);
        ushort4 st2;
        st2.x = f2bf(f4); st2.y = f2bf(f5); st2.z = f2bf(f6); st2.w = f2bf(f7);
        uint4 sv;
        sv.x = ((uint32_t)st.y  << 16) | st.x;  sv.y = ((uint32_t)st.w  << 16) | st.z;
        sv.z = ((uint32_t)st2.y << 16) | st2.x; sv.w = ((uint32_t)st2.w << 16) | st2.z;
        *reinterpret_cast<uint4*>(qn + t * DD + lane * 8) = sv;
        float4 wa0 = *reinterpret_cast<const float4*>(w_alpha + lane * 8);
        float4 wa1 = *reinterpret_cast<const float4*>(w_alpha + lane * 8 + 4);
        float al = bf2f(st.x)*wa0.x + bf2f(st.y)*wa0.y + bf2f(st.z)*wa0.z + bf2f(st.w)*wa0.w
                 + bf2f(st2.x)*wa1.x + bf2f(st2.y)*wa1.y + bf2f(st2.z)*wa1.z + bf2f(st2.w)*wa1.w;
        #pragma unroll
        for (int off = 32; off > 0; off >>= 1) al += __shfl_xor(al, off);
        if (lane == 0) alpha_raw[t] = SCALE * al;
    }
    // ---- k row
    {
        uint4 v = *reinterpret_cast<const uint4*>(kn + t * DD + lane * 8);
        float f0 = bf_lo(v.x), f1 = bf_hi(v.x), f2 = bf_lo(v.y), f3 = bf_hi(v.y);
        float f4 = bf_lo(v.z), f5 = bf_hi(v.z), f6 = bf_lo(v.w), f7 = bf_hi(v.w);
        float ss = f0*f0 + f1*f1 + f2*f2 + f3*f3 + f4*f4 + f5*f5 + f6*f6 + f7*f7;
        #pragma unroll
        for (int off = 32; off > 0; off >>= 1) ss += __shfl_xor(ss, off);
        float r = 1.0f / fmaxf(sqrtf(ss), 1e-12f);
        f0 *= r; f1 *= r; f2 *= r; f3 *= r; f4 *= r; f5 *= r; f6 *= r; f7 *= r;
        uint4 sv;
        sv.x = ((uint32_t)f2bf(f1) << 16) | f2bf(f0);
        sv.y = ((uint32_t)f2bf(f3) << 16) | f2bf(f2);
        sv.z = ((uint32_t)f2bf(f5) << 16) | f2bf(f4);
        sv.w = ((uint32_t)f2bf(f7) << 16) | f2bf(f6);
        *reinterpret_cast<uint4*>(kn + t * DD + lane * 8) = sv;
    }
}

// ---------------------------------------------------------------------------
// K2: per-batch inverse L2 norm of a [4096] vector
// ---------------------------------------------------------------------------
__global__ __launch_bounds__(256) void norm_kernel(const float* __restrict__ in,
                                                   float* __restrict__ inv_out)
{
    int b = blockIdx.x;
    __shared__ float red[256];
    float s = 0.f;
    for (int i = threadIdx.x; i < NTOKB; i += 256) {
        float v = in[b * NTOKB + i];
        s = fmaf(v, v, s);
    }
    red[threadIdx.x] = s;
    __syncthreads();
    for (int off = 128; off > 0; off >>= 1) {
        if (threadIdx.x < off) red[threadIdx.x] += red[threadIdx.x + off];
        __syncthreads();
    }
    if (threadIdx.x == 0) inv_out[b] = 1.0f / fmaxf(sqrtf(red[0]), 1e-12f);
}

// ---------------------------------------------------------------------------
// K3: dst[b,d] += sum_i raw[b,i]*inv[b] * M[b,i,d]   (fp32 atomics; dst pre-zeroed)
// ---------------------------------------------------------------------------
__global__ __launch_bounds__(256) void wsum_kernel(const ushortT* __restrict__ M,
                                                   const float* __restrict__ raw,
                                                   const float* __restrict__ invp,
                                                   float* __restrict__ dst)
{
    int blk = blockIdx.x;
    int b = blk >> 5;
    int r = blk & 31;
    int d0 = (r >> 4) * 256 + threadIdx.x;
    int i0 = (r & 15) * 256;
    const size_t rowbase = (size_t)b * NTOKB + i0;
    float acc = 0.f;
    for (int ii = 0; ii < 256; ++ii) {
        float w = raw[rowbase + ii];
        acc = fmaf(w, bf2f(M[(rowbase + ii) * DD + d0]), acc);
    }
    atomicAdd(&dst[b * DD + d0], acc * invp[b]);
}

// ---------------------------------------------------------------------------
// K4: per-batch softmax over 512; optional premultiplier; optional wb2 output.
// ---------------------------------------------------------------------------
__global__ __launch_bounds__(256) void softmax_kernel(const float* __restrict__ in,
                                                      const float* __restrict__ mul,
                                                      const float* __restrict__ wbeta,
                                                      float* __restrict__ out,
                                                      float* __restrict__ wb2)
{
    int b = blockIdx.x, tid = threadIdx.x;
    __shared__ float red[256];
    float v0 = in[b * DD + tid], v1 = in[b * DD + 256 + tid];
    if (mul) { v0 *= mul[b * DD + tid]; v1 *= mul[b * DD + 256 + tid]; }
    red[tid] = fmaxf(v0, v1);
    __syncthreads();
    for (int off = 128; off > 0; off >>= 1) {
        if (tid < off) red[tid] = fmaxf(red[tid], red[tid + off]);
        __syncthreads();
    }
    float m = red[0];
    __syncthreads();
    float e0 = expf(v0 - m), e1 = expf(v1 - m);
    red[tid] = e0 + e1;
    __syncthreads();
    for (int off = 128; off > 0; off >>= 1) {
        if (tid < off) red[tid] += red[tid + off];
        __syncthreads();
    }
    float rs = 1.0f / red[0];
    float o0 = e0 * rs, o1 = e1 * rs;
    out[b * DD + tid] = o0;
    out[b * DD + 256 + tid] = o1;
    if (wb2) {
        wb2[b * DD + tid]       = o0 * wbeta[tid];
        wb2[b * DD + 256 + tid] = o1 * wbeta[256 + tid];
    }
}

// ---------------------------------------------------------------------------
// K5: beta_raw[tok] = SCALE * dot(kn[tok,:], wb2[b,:])  — one wave per token
// ---------------------------------------------------------------------------
__global__ __launch_bounds__(256) void beta_kernel(const ushortT* __restrict__ kn,
                                                   const float* __restrict__ wb2,
                                                   float* __restrict__ beta_raw)
{
    int wave = threadIdx.x >> 6, lane = threadIdx.x & 63;
    size_t tok = (size_t)blockIdx.x * 4 + wave;
    int b = (int)(tok >> 12);
    uint4 kv = *reinterpret_cast<const uint4*>(kn + tok * DD + lane * 8);
    float4 wv0 = *reinterpret_cast<const float4*>(wb2 + b * DD + lane * 8);
    float4 wv1 = *reinterpret_cast<const float4*>(wb2 + b * DD + lane * 8 + 4);
    float s = bf_lo(kv.x) * wv0.x + bf_hi(kv.x) * wv0.y
            + bf_lo(kv.y) * wv0.z + bf_hi(kv.y) * wv0.w
            + bf_lo(kv.z) * wv1.x + bf_hi(kv.z) * wv1.y
            + bf_lo(kv.w) * wv1.z + bf_hi(kv.w) * wv1.w;
    #pragma unroll
    for (int off = 32; off > 0; off >>= 1) s += __shfl_xor(s, off);
    if (lane == 0) beta_raw[tok] = SCALE * s;
}

// ---------------------------------------------------------------------------
// K8: out = (g_k*kn + qn) @ Wr + br via MFMA. Output fp32.
// Block = 256 thr (4 waves): 64 tokens x 256 cols. K=512 in 16 chunks of 32.
// kvi tile formed bf16 in LDS each chunk (g_k from LDS copy).
// NOTE: kn ALIASES d_out — all global kn reads happen in barrier-protected
// staging before any epilogue store; blocks own disjoint token ranges.
// ---------------------------------------------------------------------------
__global__ __launch_bounds__(256) void out_mfma_kernel(
    const ushortT* __restrict__ qn, const ushortT* __restrict__ kn,
    const float* __restrict__ g_k, const ushortT* __restrict__ WrT,
    const float* __restrict__ br, float* __restrict__ out)
{
    __shared__ ushortT kvs[64 * 32];     // kvi tile [tok][k]  4 KB
    __shared__ ushortT wrs[256 * 32];    // Wr tile  [n][k]   16 KB
    __shared__ float gks[512];

    const int tid = threadIdx.x;
    const size_t tok0 = (size_t)blockIdx.x * 64;
    const int b = (int)(tok0 >> 12);

    gks[tid] = g_k[b * DD + tid];
    gks[256 + tid] = g_k[b * DD + 256 + tid];

    const int lane = tid & 63, w = tid >> 6;    // wave w -> cols [w*64, w*64+64)
    const int m = lane & 15, quad = lane >> 4;

    f32x4 acc[4][4];
    #pragma unroll
    for (int tr = 0; tr < 4; ++tr)
        #pragma unroll
        for (int tc = 0; tc < 4; ++tc) acc[tr][tc] = (f32x4){0.f, 0.f, 0.f, 0.f};

    const int st  = tid >> 2;           // token 0..63
    const int skg = (tid & 3) * 8;      // k offset 0, 8, 16, 24

    for (int c = 0; c < 16; ++c) {
        __syncthreads();   // chunk 0: gks visible; later: prev compute done
        // ---- stage kvi: 64 tok x 32 k, bf16 = g_k*kn + qn
        {
            const size_t base = (tok0 + st) * DD + c * 32 + skg;
            uint4 qv = *reinterpret_cast<const uint4*>(qn + base);
            uint4 kv = *reinterpret_cast<const uint4*>(kn + base);
            const float* g = &gks[c * 32 + skg];
            ushortT o[8];
            o[0] = f2bf(fmaf(g[0], bf_lo(kv.x), bf_lo(qv.x)));
            o[1] = f2bf(fmaf(g[1], bf_hi(kv.x), bf_hi(qv.x)));
            o[2] = f2bf(fmaf(g[2], bf_lo(kv.y), bf_lo(qv.y)));
            o[3] = f2bf(fmaf(g[3], bf_hi(kv.y), bf_hi(qv.y)));
            o[4] = f2bf(fmaf(g[4], bf_lo(kv.z), bf_lo(qv.z)));
            o[5] = f2bf(fmaf(g[5], bf_hi(kv.z), bf_hi(qv.z)));
            o[6] = f2bf(fmaf(g[6], bf_lo(kv.w), bf_lo(qv.w)));
            o[7] = f2bf(fmaf(g[7], bf_hi(kv.w), bf_hi(qv.w)));
            uint4 sv;
            sv.x = ((uint32_t)o[1] << 16) | o[0];
            sv.y = ((uint32_t)o[3] << 16) | o[2];
            sv.z = ((uint32_t)o[5] << 16) | o[4];
            sv.w = ((uint32_t)o[7] << 16) | o[6];
            *reinterpret_cast<uint4*>(&kvs[st * 32 + skg]) = sv;
        }
        // ---- stage Wr chunk: 256 n x 32 k bf16 (thread tid = row n)
        {
            const uint4* gw = reinterpret_cast<const uint4*>(WrT + (size_t)c * 8192 + tid * 32);
            uint4* lw = reinterpret_cast<uint4*>(&wrs[tid * 32]);
            #pragma unroll
            for (int i = 0; i < 4; ++i) lw[i] = gw[i];
        }
        __syncthreads();
        // ---- compute: one K=32 MFMA per (tr,tc)
        {
            short8 af[4], bfr[4];
            #pragma unroll
            for (int tr = 0; tr < 4; ++tr)
                af[tr] = *reinterpret_cast<const short8*>(&kvs[(tr * 16 + m) * 32 + quad * 8]);
            #pragma unroll
            for (int tc = 0; tc < 4; ++tc)
                bfr[tc] = *reinterpret_cast<const short8*>(&wrs[(w * 64 + tc * 16 + m) * 32 + quad * 8]);
            #pragma unroll
            for (int tr = 0; tr < 4; ++tr)
                #pragma unroll
                for (int tc = 0; tc < 4; ++tc)
                    acc[tr][tc] = __builtin_amdgcn_mfma_f32_16x16x32_bf16(af[tr], bfr[tc], acc[tr][tc], 0, 0, 0);
        }
    }

    // ---- epilogue: + br, store fp32 (overwrites kn alias range for own tokens)
    float brv[4];
    #pragma unroll
    for (int tc = 0; tc < 4; ++tc) brv[tc] = br[w * 64 + tc * 16 + m];
    #pragma unroll
    for (int tr = 0; tr < 4; ++tr) {
        #pragma unroll
        for (int reg = 0; reg < 4; ++reg) {
            size_t row = tok0 + tr * 16 + quad * 4 + reg;
            float* rp = out + row * TD + w * 64 + m;
            #pragma unroll
            for (int tc = 0; tc < 4; ++tc)
                rp[tc * 16] = acc[tr][tc][reg] + brv[tc];
        }
    }
}

// ---------------------------------------------------------------------------
extern "C" void kernel_launch(void* const* d_in, const int* in_sizes, int n_in,
                              void* d_out, int out_size, void* d_ws, size_t ws_size,
                              hipStream_t stream)
{
    const float* x       = (const float*)d_in[0];
    const float* Wq      = (const float*)d_in[1];
    const float* bq      = (const float*)d_in[2];
    const float* Wk      = (const float*)d_in[3];
    const float* bk      = (const float*)d_in[4];
    const float* Wr      = (const float*)d_in[5];
    const float* br      = (const float*)d_in[6];
    const float* w_alpha = (const float*)d_in[7];
    const float* w_beta  = (const float*)d_in[8];
    float* out = (float*)d_out;

    // kn ALIASES d_out (byte-identical token ranges); total ws ~33.7 MB.
    ushortT* kn = (ushortT*)d_out;

    char* ws = (char*)d_ws;
    ushortT* qn = (ushortT*)ws;        ws += (size_t)NTOK * DD * sizeof(ushortT);      // 32 MiB
    ushortT* W16 = (ushortT*)ws;       ws += (size_t)2 * 512 * 512 * sizeof(ushortT)
                                           + (size_t)512 * 256 * sizeof(ushortT);       // 1.25 MiB (Wq,Wk,Wr)
    float* alpha_raw = (float*)ws;     ws += (size_t)NTOK * sizeof(float);
    float* beta_raw  = (float*)ws;     ws += (size_t)NTOK * sizeof(float);
    float* gq_raw = (float*)ws;        ws += (size_t)BATCH * DD * sizeof(float);
    float* h_raw  = (float*)ws;        ws += (size_t)BATCH * DD * sizeof(float);  // contiguous w/ gq_raw
    float* g_q    = (float*)ws;        ws += (size_t)BATCH * DD * sizeof(float);
    float* wb2    = (float*)ws;        ws += (size_t)BATCH * DD * sizeof(float);
    float* g_k    = (float*)ws;        ws += (size_t)BATCH * DD * sizeof(float);
    float* inv_a  = (float*)ws;        ws += 64;
    float* inv_b  = (float*)ws;        ws += 64;
    ushortT* WrT = W16 + (size_t)2 * 512 * 512;

    hipMemsetAsync(gq_raw, 0, 2 * BATCH * DD * sizeof(float), stream);

    packw_kernel<<<48, 256, 0, stream>>>(Wq, Wk, Wr, W16);
    gemm_qk_kernel<<<dim3(NTOK / 64, 2), 512, 0, stream>>>(x, W16, bq, bk, qn, kn);
    normalize_kernel<<<NTOK / 4, 256, 0, stream>>>(qn, kn, w_alpha, alpha_raw);
    norm_kernel<<<BATCH, 256, 0, stream>>>(alpha_raw, inv_a);
    wsum_kernel<<<256, 256, 0, stream>>>(qn, alpha_raw, inv_a, gq_raw);
    softmax_kernel<<<BATCH, 256, 0, stream>>>(gq_raw, nullptr, w_beta, g_q, wb2);
    beta_kernel<<<NTOK / 4, 256, 0, stream>>>(kn, wb2, beta_raw);
    norm_kernel<<<BATCH, 256, 0, stream>>>(beta_raw, inv_b);
    wsum_kernel<<<256, 256, 0, stream>>>(kn, beta_raw, inv_b, h_raw);
    softmax_kernel<<<BATCH, 256, 0, stream>>>(h_raw, g_q, nullptr, g_k, nullptr);
    out_mfma_kernel<<<NTOK / 64, 256, 0, stream>>>(qn, kn, g_k, WrT, br, out);
}

// Round 8
// 253.491 us; speedup vs baseline: 2.7478x; 1.1238x over previous
//
#include <hip/hip_runtime.h>
#include <hip/hip_bf16.h>
#include <stdint.h>

// Problem constants (fixed by setup_inputs)
#define BATCH    8
#define NTOKB    4096                 // tokens per batch
#define NTOK     (BATCH * NTOKB)     // 32768
#define DIN      512
#define DD       512                 // TOKEN_DIM * NUM_HEADS
#define TD       256                 // TOKEN_DIM
#define SCALE    0.0625f             // 256^-0.5
#define LSTR     36                  // LDS row stride in ushorts (72 B): bank-
                                     // map m*18+q*4 mod 32 is 2-to-1 = free

typedef unsigned short ushortT;
typedef __attribute__((ext_vector_type(8))) short  short8;   // 8 bf16 = 4 VGPR
typedef __attribute__((ext_vector_type(4))) float  f32x4;

union Frag { uint4 u; short8 s; };

__device__ __forceinline__ float bf_lo(uint32_t u) { return __uint_as_float(u << 16); }
__device__ __forceinline__ float bf_hi(uint32_t u) { return __uint_as_float(u & 0xffff0000u); }
__device__ __forceinline__ float bf2f(ushortT u) { return __uint_as_float(((uint32_t)u) << 16); }
// round-to-nearest-even f32 -> bf16
__device__ __forceinline__ ushortT f2bf(float f) {
    uint32_t u = __float_as_uint(f);
    return (ushortT)((u + 0x7fffu + ((u >> 16) & 1u)) >> 16);
}
// two 8-byte LDS reads (avoids the b128 8-way-conflict trap with 72B rows)
__device__ __forceinline__ short8 lds_frag(const ushortT* p) {
    uint2 a = *reinterpret_cast<const uint2*>(p);
    uint2 b = *reinterpret_cast<const uint2*>(p + 4);
    Frag f; f.u.x = a.x; f.u.y = a.y; f.u.z = b.x; f.u.w = b.y;
    return f.s;
}

// ---------------------------------------------------------------------------
// K0: pack weights fp32 -> bf16 chunk-tiled B^T form [chunk][n][k32] (dense).
// blocks 0..15: Wq, 16..31: Wk (n=512), 32..47: Wr (n=256).
// ---------------------------------------------------------------------------
__global__ __launch_bounds__(256) void packw_kernel(
    const float* __restrict__ Wq, const float* __restrict__ Wk,
    const float* __restrict__ Wr, ushortT* __restrict__ W16)
{
    const int blk = blockIdx.x;
    if (blk < 32) {
        const int mat = blk >> 4, c = blk & 15;
        const float* S = mat ? Wk : Wq;
        ushortT* D = W16 + (size_t)mat * (512 * 512) + (size_t)c * 16384;
        for (int i = threadIdx.x; i < 16384; i += 256) {
            int n = i & 511, kk = i >> 9;             // consecutive n -> coalesced read
            D[n * 32 + kk] = f2bf(S[(size_t)(c * 32 + kk) * 512 + n]);
        }
    } else {
        const int c = blk - 32;
        ushortT* D = W16 + (size_t)2 * (512 * 512) + (size_t)c * 8192;
        for (int i = threadIdx.x; i < 8192; i += 256) {
            int n = i & 255, kk = i >> 8;
            D[n * 32 + kk] = f2bf(Wr[(size_t)(c * 32 + kk) * 256 + n]);
        }
    }
}

// ---------------------------------------------------------------------------
// K6: MFMA GEMM + FUSED l2norm + alpha: qn/kn = l2norm(x@W + bias) in bf16;
// alpha_raw[t] = SCALE * dot(qn_fp32, w_alpha) (mat==0 only).
// Block = 512 thr (8 waves): 64 tokens x ALL 512 cols (full rows -> fusable).
// Wave = 64x64 (4x4 tiles of 16x16x32). K=512 staged in 16 chunks of 32.
// Lane fragments: A[m=lane&15][k=quad*8+j], B[n=lane&15][k=quad*8+j] (B^T LDS);
// D: col=lane&15, row=quad*4+reg (verified m89/m91).
// ---------------------------------------------------------------------------
__global__ __launch_bounds__(512) void gemm_qk_kernel(
    const float* __restrict__ x, const ushortT* __restrict__ W16,
    const float* __restrict__ bq, const float* __restrict__ bk,
    const float* __restrict__ w_alpha,
    ushortT* __restrict__ qn, ushortT* __restrict__ kn,
    float* __restrict__ alpha_raw)
{
    __shared__ ushortT xs[64 * LSTR];      // x tile  [tok][k]   4.5 KB
    __shared__ ushortT wsd[512 * LSTR];    // W tile  [n][k]    36 KB
    __shared__ float rowsq[8][64];
    __shared__ float alphap[8][64];
    __shared__ float rnorm_s[64];

    const int tid = threadIdx.x;
    const int mat = blockIdx.y;
    const size_t tok0 = (size_t)blockIdx.x * 64;
    const ushortT* Wb = W16 + (size_t)mat * (512 * 512);
    const float* bias = mat ? bk : bq;
    ushortT* dst = mat ? kn : qn;

    const int lane = tid & 63, w = tid >> 6;    // wave w -> cols [w*64, w*64+64)
    const int m = lane & 15, quad = lane >> 4;

    f32x4 acc[4][4];
    #pragma unroll
    for (int tr = 0; tr < 4; ++tr)
        #pragma unroll
        for (int tc = 0; tc < 4; ++tc) acc[tr][tc] = (f32x4){0.f, 0.f, 0.f, 0.f};

    const int xtok = tid >> 3;                 // 0..63
    const int xkg  = (tid & 7) * 4;            // 0..28
    const float* xsrc = x + (tok0 + xtok) * DIN;
    const int wr_r = tid >> 2;                 // 0..127
    const int wseg = (tid & 3) * 8;            // ushort offset 0,8,16,24

    for (int c = 0; c < 16; ++c) {
        __syncthreads();
        // ---- stage x: 64 tok x 32 k, fp32 -> bf16 (8B writes)
        {
            float4 xv = *reinterpret_cast<const float4*>(xsrc + c * 32 + xkg);
            ushort4 xb;
            xb.x = f2bf(xv.x); xb.y = f2bf(xv.y); xb.z = f2bf(xv.z); xb.w = f2bf(xv.w);
            *reinterpret_cast<ushort4*>(&xs[xtok * LSTR + xkg]) = xb;
        }
        // ---- stage W chunk: 512 n x 32 k bf16; global 16B coalesced, LDS 8B
        #pragma unroll
        for (int rr = 0; rr < 4; ++rr) {
            int r = wr_r + rr * 128;
            uint4 gv = *reinterpret_cast<const uint4*>(Wb + (size_t)c * 16384 + r * 32 + wseg);
            uint2* lp = reinterpret_cast<uint2*>(&wsd[r * LSTR + wseg]);
            lp[0] = make_uint2(gv.x, gv.y);
            lp[1] = make_uint2(gv.z, gv.w);
        }
        __syncthreads();
        // ---- compute: one K=32 MFMA per (tr,tc)
        {
            short8 af[4], bf[4];
            #pragma unroll
            for (int tr = 0; tr < 4; ++tr)
                af[tr] = lds_frag(&xs[(tr * 16 + m) * LSTR + quad * 8]);
            #pragma unroll
            for (int tc = 0; tc < 4; ++tc)
                bf[tc] = lds_frag(&wsd[(w * 64 + tc * 16 + m) * LSTR + quad * 8]);
            #pragma unroll
            for (int tr = 0; tr < 4; ++tr)
                #pragma unroll
                for (int tc = 0; tc < 4; ++tc)
                    acc[tr][tc] = __builtin_amdgcn_mfma_f32_16x16x32_bf16(af[tr], bf[tc], acc[tr][tc], 0, 0, 0);
        }
    }

    // ---- fused epilogue: bias, row ssq + alpha partials, normalize, store
    float biasv[4], wa[4];
    #pragma unroll
    for (int tc = 0; tc < 4; ++tc) {
        biasv[tc] = bias[w * 64 + tc * 16 + m];
        wa[tc] = (mat == 0) ? w_alpha[w * 64 + tc * 16 + m] : 0.f;
    }
    #pragma unroll
    for (int tr = 0; tr < 4; ++tr)
        #pragma unroll
        for (int tc = 0; tc < 4; ++tc)
            #pragma unroll
            for (int reg = 0; reg < 4; ++reg)
                acc[tr][tc][reg] += biasv[tc];

    __syncthreads();   // compute done everywhere before reusing LDS barriers
    #pragma unroll
    for (int tr = 0; tr < 4; ++tr) {
        #pragma unroll
        for (int reg = 0; reg < 4; ++reg) {
            float s = 0.f, a = 0.f;
            #pragma unroll
            for (int tc = 0; tc < 4; ++tc) {
                float v = acc[tr][tc][reg];
                s = fmaf(v, v, s);
                a = fmaf(v, wa[tc], a);
            }
            // reduce over the 16 m-lanes of this quad
            #pragma unroll
            for (int off = 1; off < 16; off <<= 1) {
                s += __shfl_xor(s, off);
                a += __shfl_xor(a, off);
            }
            if (m == 0) {
                rowsq[w][tr * 16 + quad * 4 + reg] = s;
                alphap[w][tr * 16 + quad * 4 + reg] = a;
            }
        }
    }
    __syncthreads();
    if (tid < 64) {
        float ss = 0.f, aa = 0.f;
        #pragma unroll
        for (int w2 = 0; w2 < 8; ++w2) { ss += rowsq[w2][tid]; aa += alphap[w2][tid]; }
        float rn = 1.0f / fmaxf(sqrtf(ss), 1e-12f);
        rnorm_s[tid] = rn;
        if (mat == 0) alpha_raw[tok0 + tid] = SCALE * aa * rn;
    }
    __syncthreads();
    #pragma unroll
    for (int tr = 0; tr < 4; ++tr) {
        #pragma unroll
        for (int reg = 0; reg < 4; ++reg) {
            float rn = rnorm_s[tr * 16 + quad * 4 + reg];
            size_t row = tok0 + tr * 16 + quad * 4 + reg;
            ushortT* rp = dst + row * DD + w * 64 + m;
            #pragma unroll
            for (int tc = 0; tc < 4; ++tc)
                rp[tc * 16] = f2bf(acc[tr][tc][reg] * rn);
        }
    }
}

// ---------------------------------------------------------------------------
// K2: per-batch inverse L2 norm of a [4096] vector
// ---------------------------------------------------------------------------
__global__ __launch_bounds__(256) void norm_kernel(const float* __restrict__ in,
                                                   float* __restrict__ inv_out)
{
    int b = blockIdx.x;
    __shared__ float red[256];
    float s = 0.f;
    for (int i = threadIdx.x; i < NTOKB; i += 256) {
        float v = in[b * NTOKB + i];
        s = fmaf(v, v, s);
    }
    red[threadIdx.x] = s;
    __syncthreads();
    for (int off = 128; off > 0; off >>= 1) {
        if (threadIdx.x < off) red[threadIdx.x] += red[threadIdx.x + off];
        __syncthreads();
    }
    if (threadIdx.x == 0) inv_out[b] = 1.0f / fmaxf(sqrtf(red[0]), 1e-12f);
}

// ---------------------------------------------------------------------------
// K3: dst[b,d] += sum_i raw[b,i]*inv[b] * M[b,i,d]   (fp32 atomics; dst pre-zeroed)
// grid = 256 blocks: b(8) x iseg(32, 128 rows each). Thread owns col pair
// 2*tid; rows read as contiguous uint words (1 KB/wave, coalesced).
// ---------------------------------------------------------------------------
__global__ __launch_bounds__(256) void wsum_kernel(const ushortT* __restrict__ M,
                                                   const float* __restrict__ raw,
                                                   const float* __restrict__ invp,
                                                   float* __restrict__ dst)
{
    const int blk = blockIdx.x, tid = threadIdx.x;
    const int b = blk >> 5;
    const int i0 = (blk & 31) * 128;
    __shared__ float wr[128];
    if (tid < 128) wr[tid] = raw[(size_t)b * NTOKB + i0 + tid];
    __syncthreads();
    const uint32_t* M32 = reinterpret_cast<const uint32_t*>(M);
    size_t base = ((size_t)b * NTOKB + i0) * 256 + tid;
    float a0 = 0.f, a1 = 0.f;
    for (int ii = 0; ii < 128; ++ii) {
        uint32_t v = M32[base + (size_t)ii * 256];
        float wv = wr[ii];
        a0 = fmaf(wv, bf_lo(v), a0);
        a1 = fmaf(wv, bf_hi(v), a1);
    }
    float iv = invp[b];
    atomicAdd(&dst[b * DD + 2 * tid],     a0 * iv);
    atomicAdd(&dst[b * DD + 2 * tid + 1], a1 * iv);
}

// ---------------------------------------------------------------------------
// K4: per-batch softmax over 512; optional premultiplier; optional wb2 output.
// ---------------------------------------------------------------------------
__global__ __launch_bounds__(256) void softmax_kernel(const float* __restrict__ in,
                                                      const float* __restrict__ mul,
                                                      const float* __restrict__ wbeta,
                                                      float* __restrict__ out,
                                                      float* __restrict__ wb2)
{
    int b = blockIdx.x, tid = threadIdx.x;
    __shared__ float red[256];
    float v0 = in[b * DD + tid], v1 = in[b * DD + 256 + tid];
    if (mul) { v0 *= mul[b * DD + tid]; v1 *= mul[b * DD + 256 + tid]; }
    red[tid] = fmaxf(v0, v1);
    __syncthreads();
    for (int off = 128; off > 0; off >>= 1) {
        if (tid < off) red[tid] = fmaxf(red[tid], red[tid + off]);
        __syncthreads();
    }
    float m = red[0];
    __syncthreads();
    float e0 = expf(v0 - m), e1 = expf(v1 - m);
    red[tid] = e0 + e1;
    __syncthreads();
    for (int off = 128; off > 0; off >>= 1) {
        if (tid < off) red[tid] += red[tid + off];
        __syncthreads();
    }
    float rs = 1.0f / red[0];
    float o0 = e0 * rs, o1 = e1 * rs;
    out[b * DD + tid] = o0;
    out[b * DD + 256 + tid] = o1;
    if (wb2) {
        wb2[b * DD + tid]       = o0 * wbeta[tid];
        wb2[b * DD + 256 + tid] = o1 * wbeta[256 + tid];
    }
}

// ---------------------------------------------------------------------------
// K5: beta_raw[tok] = SCALE * dot(kn[tok,:], wb2[b,:])  — one wave per token
// ---------------------------------------------------------------------------
__global__ __launch_bounds__(256) void beta_kernel(const ushortT* __restrict__ kn,
                                                   const float* __restrict__ wb2,
                                                   float* __restrict__ beta_raw)
{
    int wave = threadIdx.x >> 6, lane = threadIdx.x & 63;
    size_t tok = (size_t)blockIdx.x * 4 + wave;
    int b = (int)(tok >> 12);
    uint4 kv = *reinterpret_cast<const uint4*>(kn + tok * DD + lane * 8);
    float4 wv0 = *reinterpret_cast<const float4*>(wb2 + b * DD + lane * 8);
    float4 wv1 = *reinterpret_cast<const float4*>(wb2 + b * DD + lane * 8 + 4);
    float s = bf_lo(kv.x) * wv0.x + bf_hi(kv.x) * wv0.y
            + bf_lo(kv.y) * wv0.z + bf_hi(kv.y) * wv0.w
            + bf_lo(kv.z) * wv1.x + bf_hi(kv.z) * wv1.y
            + bf_lo(kv.w) * wv1.z + bf_hi(kv.w) * wv1.w;
    #pragma unroll
    for (int off = 32; off > 0; off >>= 1) s += __shfl_xor(s, off);
    if (lane == 0) beta_raw[tok] = SCALE * s;
}

// ---------------------------------------------------------------------------
// K8: out = (g_k*kn + qn) @ Wr + br via MFMA. Output fp32.
// Block = 256 thr (4 waves): 64 tokens x 256 cols. K=512 in 16 chunks of 32.
// 72B LDS rows (same bank-conflict fix as gemm).
// NOTE: kn ALIASES d_out — all global kn reads happen in barrier-protected
// staging before any epilogue store; blocks own disjoint token ranges.
// ---------------------------------------------------------------------------
__global__ __launch_bounds__(256) void out_mfma_kernel(
    const ushortT* __restrict__ qn, const ushortT* __restrict__ kn,
    const float* __restrict__ g_k, const ushortT* __restrict__ WrT,
    const float* __restrict__ br, float* __restrict__ out)
{
    __shared__ ushortT kvs[64 * LSTR];     // kvi tile [tok][k]   4.5 KB
    __shared__ ushortT wrs[256 * LSTR];    // Wr tile  [n][k]    18 KB
    __shared__ float gks[512];

    const int tid = threadIdx.x;
    const size_t tok0 = (size_t)blockIdx.x * 64;
    const int b = (int)(tok0 >> 12);

    gks[tid] = g_k[b * DD + tid];
    gks[256 + tid] = g_k[b * DD + 256 + tid];

    const int lane = tid & 63, w = tid >> 6;    // wave w -> cols [w*64, w*64+64)
    const int m = lane & 15, quad = lane >> 4;

    f32x4 acc[4][4];
    #pragma unroll
    for (int tr = 0; tr < 4; ++tr)
        #pragma unroll
        for (int tc = 0; tc < 4; ++tc) acc[tr][tc] = (f32x4){0.f, 0.f, 0.f, 0.f};

    const int st  = tid >> 2;           // token 0..63
    const int skg = (tid & 3) * 8;      // k offset 0, 8, 16, 24
    const int wr_r = tid >> 2;          // 0..63
    const int wseg = (tid & 3) * 8;

    for (int c = 0; c < 16; ++c) {
        __syncthreads();   // chunk 0: gks visible; later: prev compute done
        // ---- stage kvi: 64 tok x 32 k, bf16 = g_k*kn + qn  (8B LDS writes)
        {
            const size_t base = (tok0 + st) * DD + c * 32 + skg;
            uint4 qv = *reinterpret_cast<const uint4*>(qn + base);
            uint4 kv = *reinterpret_cast<const uint4*>(kn + base);
            const float* g = &gks[c * 32 + skg];
            ushortT o[8];
            o[0] = f2bf(fmaf(g[0], bf_lo(kv.x), bf_lo(qv.x)));
            o[1] = f2bf(fmaf(g[1], bf_hi(kv.x), bf_hi(qv.x)));
            o[2] = f2bf(fmaf(g[2], bf_lo(kv.y), bf_lo(qv.y)));
            o[3] = f2bf(fmaf(g[3], bf_hi(kv.y), bf_hi(qv.y)));
            o[4] = f2bf(fmaf(g[4], bf_lo(kv.z), bf_lo(qv.z)));
            o[5] = f2bf(fmaf(g[5], bf_hi(kv.z), bf_hi(qv.z)));
            o[6] = f2bf(fmaf(g[6], bf_lo(kv.w), bf_lo(qv.w)));
            o[7] = f2bf(fmaf(g[7], bf_hi(kv.w), bf_hi(qv.w)));
            uint2* lp = reinterpret_cast<uint2*>(&kvs[st * LSTR + skg]);
            lp[0] = make_uint2(((uint32_t)o[1] << 16) | o[0], ((uint32_t)o[3] << 16) | o[2]);
            lp[1] = make_uint2(((uint32_t)o[5] << 16) | o[4], ((uint32_t)o[7] << 16) | o[6]);
        }
        // ---- stage Wr chunk: 256 n x 32 k bf16
        #pragma unroll
        for (int rr = 0; rr < 4; ++rr) {
            int r = wr_r + rr * 64;
            uint4 gv = *reinterpret_cast<const uint4*>(WrT + (size_t)c * 8192 + r * 32 + wseg);
            uint2* lp = reinterpret_cast<uint2*>(&wrs[r * LSTR + wseg]);
            lp[0] = make_uint2(gv.x, gv.y);
            lp[1] = make_uint2(gv.z, gv.w);
        }
        __syncthreads();
        // ---- compute: one K=32 MFMA per (tr,tc)
        {
            short8 af[4], bfr[4];
            #pragma unroll
            for (int tr = 0; tr < 4; ++tr)
                af[tr] = lds_frag(&kvs[(tr * 16 + m) * LSTR + quad * 8]);
            #pragma unroll
            for (int tc = 0; tc < 4; ++tc)
                bfr[tc] = lds_frag(&wrs[(w * 64 + tc * 16 + m) * LSTR + quad * 8]);
            #pragma unroll
            for (int tr = 0; tr < 4; ++tr)
                #pragma unroll
                for (int tc = 0; tc < 4; ++tc)
                    acc[tr][tc] = __builtin_amdgcn_mfma_f32_16x16x32_bf16(af[tr], bfr[tc], acc[tr][tc], 0, 0, 0);
        }
    }

    // ---- epilogue: + br, store fp32 (overwrites kn alias range for own tokens)
    float brv[4];
    #pragma unroll
    for (int tc = 0; tc < 4; ++tc) brv[tc] = br[w * 64 + tc * 16 + m];
    #pragma unroll
    for (int tr = 0; tr < 4; ++tr) {
        #pragma unroll
        for (int reg = 0; reg < 4; ++reg) {
            size_t row = tok0 + tr * 16 + quad * 4 + reg;
            float* rp = out + row * TD + w * 64 + m;
            #pragma unroll
            for (int tc = 0; tc < 4; ++tc)
                rp[tc * 16] = acc[tr][tc][reg] + brv[tc];
        }
    }
}

// ---------------------------------------------------------------------------
extern "C" void kernel_launch(void* const* d_in, const int* in_sizes, int n_in,
                              void* d_out, int out_size, void* d_ws, size_t ws_size,
                              hipStream_t stream)
{
    const float* x       = (const float*)d_in[0];
    const float* Wq      = (const float*)d_in[1];
    const float* bq      = (const float*)d_in[2];
    const float* Wk      = (const float*)d_in[3];
    const float* bk      = (const float*)d_in[4];
    const float* Wr      = (const float*)d_in[5];
    const float* br      = (const float*)d_in[6];
    const float* w_alpha = (const float*)d_in[7];
    const float* w_beta  = (const float*)d_in[8];
    float* out = (float*)d_out;

    // kn ALIASES d_out (byte-identical token ranges); total ws ~33.7 MB.
    ushortT* kn = (ushortT*)d_out;

    char* ws = (char*)d_ws;
    ushortT* qn = (ushortT*)ws;        ws += (size_t)NTOK * DD * sizeof(ushortT);      // 32 MiB
    ushortT* W16 = (ushortT*)ws;       ws += (size_t)2 * 512 * 512 * sizeof(ushortT)
                                           + (size_t)512 * 256 * sizeof(ushortT);       // 1.25 MiB (Wq,Wk,Wr)
    float* alpha_raw = (float*)ws;     ws += (size_t)NTOK * sizeof(float);
    float* beta_raw  = (float*)ws;     ws += (size_t)NTOK * sizeof(float);
    float* gq_raw = (float*)ws;        ws += (size_t)BATCH * DD * sizeof(float);
    float* h_raw  = (float*)ws;        ws += (size_t)BATCH * DD * sizeof(float);  // contiguous w/ gq_raw
    float* g_q    = (float*)ws;        ws += (size_t)BATCH * DD * sizeof(float);
    float* wb2    = (float*)ws;        ws += (size_t)BATCH * DD * sizeof(float);
    float* g_k    = (float*)ws;        ws += (size_t)BATCH * DD * sizeof(float);
    float* inv_a  = (float*)ws;        ws += 64;
    float* inv_b  = (float*)ws;        ws += 64;
    ushortT* WrT = W16 + (size_t)2 * 512 * 512;

    hipMemsetAsync(gq_raw, 0, 2 * BATCH * DD * sizeof(float), stream);

    packw_kernel<<<48, 256, 0, stream>>>(Wq, Wk, Wr, W16);
    gemm_qk_kernel<<<dim3(NTOK / 64, 2), 512, 0, stream>>>(x, W16, bq, bk, w_alpha, qn, kn, alpha_raw);
    norm_kernel<<<BATCH, 256, 0, stream>>>(alpha_raw, inv_a);
    wsum_kernel<<<256, 256, 0, stream>>>(qn, alpha_raw, inv_a, gq_raw);
    softmax_kernel<<<BATCH, 256, 0, stream>>>(gq_raw, nullptr, w_beta, g_q, wb2);
    beta_kernel<<<NTOK / 4, 256, 0, stream>>>(kn, wb2, beta_raw);
    norm_kernel<<<BATCH, 256, 0, stream>>>(beta_raw, inv_b);
    wsum_kernel<<<256, 256, 0, stream>>>(kn, beta_raw, inv_b, h_raw);
    softmax_kernel<<<BATCH, 256, 0, stream>>>(h_raw, g_q, nullptr, g_k, nullptr);
    out_mfma_kernel<<<NTOK / 64, 256, 0, stream>>>(qn, kn, g_k, WrT, br, out);
}